// Round 3
// baseline (245.910 us; speedup 1.0000x reference)
//
#include <hip/hip_runtime.h>
#include <math.h>

#define BB 131072
#define HH 64
#define NOB 32
#define NDIRS 8
#define LR_IT 1e-3f
#define TOLV 1e-3f
#define EPSV 1e-6f
#define NBLK 512
#define TPB 256
#define WRS 68   // LDS row stride (floats) for Wr / WinT: 68*4=272B, 16B-aligned
#define WOS 36   // LDS row stride for WoutT: 36*4=144B, 16B-aligned
#define INV_BH (1.0f/8388608.0f)   // 1/(B*H)

// NOTE: macro params must not be named x/y/z/w — textual expansion rewrites
// member accesses like (pp).w otherwise.
#define D16(pp, Wp, b) ((pp).x*(Wp)[(b)+0] + (pp).y*(Wp)[(b)+1] + (pp).z*(Wp)[(b)+2] + (pp).w*(Wp)[(b)+3])
#define DOT64P(Wp) (D16(p0,Wp,0)+D16(p1,Wp,4)+D16(p2,Wp,8)+D16(p3,Wp,12)+ \
                    D16(p4,Wp,16)+D16(p5,Wp,20)+D16(p6,Wp,24)+D16(p7,Wp,28)+ \
                    D16(p8,Wp,32)+D16(p9,Wp,36)+D16(p10,Wp,40)+D16(p11,Wp,44)+ \
                    D16(p12,Wp,48)+D16(p13,Wp,52)+D16(p14,Wp,56)+D16(p15,Wp,60))
#define LOADP(src) \
  float4 p0=(src)[0], p1=(src)[1], p2=(src)[2], p3=(src)[3], \
         p4=(src)[4], p5=(src)[5], p6=(src)[6], p7=(src)[7], \
         p8=(src)[8], p9=(src)[9], p10=(src)[10], p11=(src)[11], \
         p12=(src)[12], p13=(src)[13], p14=(src)[14], p15=(src)[15];
#define SUMSQ4(pp) ((pp).x*(pp).x + (pp).y*(pp).y + (pp).z*(pp).z + (pp).w*(pp).w)
#define SUM4(pp) ((pp).x + (pp).y + (pp).z + (pp).w)

// ---- LDS staging: each block copies weights straight from global ----
__device__ __forceinline__ void stage_wr(const float* __restrict__ Wr, float* wrl, int t) {
  const float4* g = (const float4*)Wr;           // Wr row-major [64][64]
  for (int i = t; i < 1024; i += TPB) {
    int h = i >> 4, k4 = i & 15;
    *(float4*)&wrl[h * WRS + k4 * 4] = g[i];     // linear copy, padded rows
  }
}
__device__ __forceinline__ void stage_wot(const float* __restrict__ Wout, float* wot, int t) {
  for (int i = t; i < NOB * HH; i += TPB) {      // Wout [32][64] -> wot[h][o]
    int o = i >> 6, h = i & 63;
    wot[h * WOS + o] = Wout[i];
  }
}
__device__ __forceinline__ void stage_wint(const float* __restrict__ Win, float* wint, int t) {
  for (int i = t; i < HH * NDIRS; i += TPB) {    // Win [64][8] -> wint[d][h]
    int h = i >> 3, d = i & 7;
    wint[d * WRS + h] = Win[i];
  }
}

// ---- init: prev = norm(x) (kept implicit as x + sclX); s0 raw -> buf0, scale -> scl0 ----
__global__ __launch_bounds__(TPB, 2) void init_kernel(
    const float* __restrict__ x, const int* __restrict__ dirs,
    const float* __restrict__ Wr, const float* __restrict__ Win,
    float* __restrict__ buf0, float* __restrict__ sclX, float* __restrict__ scl0,
    float* __restrict__ partials)
{
  __shared__ float wrl[HH * WRS];
  __shared__ float wint[NDIRS * WRS];
  __shared__ float red[4];
  int t = threadIdx.x;
  stage_wr(Wr, wrl, t);
  stage_wint(Win, wint, t);
  __syncthreads();

  int r = blockIdx.x * TPB + t;
  const float4* xr = (const float4*)(x + (size_t)r * HH);
  LOADP(xr);

  float ssx = SUMSQ4(p0)+SUMSQ4(p1)+SUMSQ4(p2)+SUMSQ4(p3)+SUMSQ4(p4)+SUMSQ4(p5)+
              SUMSQ4(p6)+SUMSQ4(p7)+SUMSQ4(p8)+SUMSQ4(p9)+SUMSQ4(p10)+SUMSQ4(p11)+
              SUMSQ4(p12)+SUMSQ4(p13)+SUMSQ4(p14)+SUMSQ4(p15);
  float sx  = SUM4(p0)+SUM4(p1)+SUM4(p2)+SUM4(p3)+SUM4(p4)+SUM4(p5)+SUM4(p6)+SUM4(p7)+
              SUM4(p8)+SUM4(p9)+SUM4(p10)+SUM4(p11)+SUM4(p12)+SUM4(p13)+SUM4(p14)+SUM4(p15);
  float inv_x = 1.f / (sqrtf(ssx) + EPSV);
  int dir = dirs[r];

  float4* bo = (float4*)(buf0 + (size_t)r * HH);
  float ssg = 0.f, sg = 0.f;
#define INIT_ONE(JJ, COMP) { \
    const float* wr_ = &wrl[(h0 * 4 + JJ) * WRS]; \
    u.COMP = fmaxf(fmaf(inv_x, DOT64P(wr_), d4.COMP), 0.f); }
  #pragma unroll 1
  for (int h0 = 0; h0 < 16; ++h0) {
    float4 d4 = *(const float4*)&wint[dir * WRS + h0 * 4];
    float4 u;
    INIT_ONE(0, x) INIT_ONE(1, y) INIT_ONE(2, z) INIT_ONE(3, w)
    bo[h0] = u;
    ssg += SUMSQ4(u); sg += SUM4(u);
  }
  float inv_g = 1.f / (sqrtf(ssg) + EPSV);
  sclX[r] = inv_x;
  scl0[r] = inv_g;

  float pv_ = inv_x * sx - inv_g * sg;   // sum(prev - s0) for this row
  #pragma unroll
  for (int off = 32; off > 0; off >>= 1) pv_ += __shfl_down(pv_, off);
  if ((t & 63) == 0) red[t >> 6] = pv_;
  __syncthreads();
  if (t == 0) partials[blockIdx.x] = red[0] + red[1] + red[2] + red[3];
}

// ---- one gated iteration; gate is re-reduced from partials by every block ----
__global__ __launch_bounds__(TPB, 2) void step_kernel(
    const float* __restrict__ x,
    float* __restrict__ buf0, float* __restrict__ buf1,
    const float* __restrict__ sclX, float* __restrict__ scl0, float* __restrict__ scl1,
    const float* __restrict__ Wr, const float* __restrict__ Wout, const float* __restrict__ Win,
    const int* __restrict__ dirs, const int* __restrict__ obs,
    float* __restrict__ partials, int* __restrict__ actArr, int k)
{
  __shared__ float red[4];
  __shared__ float wrl[HH * WRS];
  __shared__ float wot[HH * WOS];
  __shared__ float wint[NDIRS * WRS];
  int t = threadIdx.x;

  // gate: reduce partials (all blocks compute the identical value)
  float v = partials[t] + partials[t + TPB];
  #pragma unroll
  for (int off = 32; off > 0; off >>= 1) v += __shfl_down(v, off);
  if ((t & 63) == 0) red[t >> 6] = v;
  __syncthreads();
  float tot = red[0] + red[1] + red[2] + red[3];
  int active = (fabsf(tot * INV_BH) > TOLV) ? 1 : 0;
  if (blockIdx.x == 0 && t == 0) actArr[k] = active;
  if (!active) return;

  int p = 0;
  for (int j = 0; j < k; ++j) p += actArr[j];   // #active steps before this one
  int si = p & 1;
  const float* S    = si ? buf1 : buf0;
  const float* sclS = si ? scl1 : scl0;
  const float* P    = (p == 0) ? x    : (si ? buf0 : buf1);
  const float* sclP = (p == 0) ? sclX : (si ? scl0 : scl1);
  float* W    = si ? buf0 : buf1;               // overwrite prev buffer (RAW->WAR safe per-thread)
  float* sclW = si ? scl0 : scl1;

  stage_wr(Wr, wrl, t);
  stage_wot(Wout, wot, t);
  stage_wint(Win, wint, t);
  __syncthreads();

  int r = blockIdx.x * TPB + t;
  float a_s = sclS[r];
  float a_p = sclP[r];
  const float4* sr4 = (const float4*)(S + (size_t)r * HH);
  const float4* pr4 = (const float4*)(P + (size_t)r * HH);
  LOADP(pr4);   // prev row lives in named registers for phase B dots

  // phase A: logits (raw scale), via transposed Wout rows
  float zz[NOB];
  #pragma unroll
  for (int o = 0; o < NOB; ++o) zz[o] = 0.f;
  float sS = 0.f;
  #pragma unroll 1
  for (int h0 = 0; h0 < 16; ++h0) {
    float4 s4 = sr4[h0];
    sS += SUM4(s4);
    const float* t0 = &wot[(h0 * 4 + 0) * WOS];
    const float* t1 = &wot[(h0 * 4 + 1) * WOS];
    const float* t2 = &wot[(h0 * 4 + 2) * WOS];
    const float* t3 = &wot[(h0 * 4 + 3) * WOS];
    #pragma unroll
    for (int o = 0; o < NOB; ++o)
      zz[o] += s4.x * t0[o] + s4.y * t1[o] + s4.z * t2[o] + s4.w * t3[o];
  }

  // softmax (logits = a_s*zz; a_s>0 so max commutes) then zz -> jp in place
  float m = -1e30f;
  #pragma unroll
  for (int o = 0; o < NOB; ++o) m = fmaxf(m, zz[o]);
  float se = 0.f;
  #pragma unroll
  for (int o = 0; o < NOB; ++o) { zz[o] = __expf(a_s * (zz[o] - m)); se += zz[o]; }
  float rse = 1.f / se;
  int ob = obs[r];
  float fob = 0.f, sf2 = 0.f;
  #pragma unroll
  for (int o = 0; o < NOB; ++o) {
    float f = zz[o] * rse;
    zz[o] = f;
    sf2 += f * f;
    fob += (o == ob) ? f : 0.f;
  }
  float fe = fob - sf2;
  #pragma unroll
  for (int o = 0; o < NOB; ++o) {
    float ep = ((o == ob) ? 1.f : 0.f) - zz[o];
    zz[o] = zz[o] * (ep - fe);   // jp
  }

  // fused phase B+C: per output h, dot64(P, Wr_row_h) and dot32(jp, WoutT_row_h)
  int dir = dirs[r];
  float4* wo4 = (float4*)(W + (size_t)r * HH);
  float ssu = 0.f, su = 0.f;
#define STEP_C_ONE(JJ, COMP) { \
    const float* wr_ = &wrl[(h0 * 4 + JJ) * WRS]; \
    float g_ = fmaxf(fmaf(a_p, DOT64P(wr_), d4.COMP), 0.f); \
    const float* wt_ = &wot[(h0 * 4 + JJ) * WOS]; \
    float w_ = 0.f; \
    _Pragma("unroll") \
    for (int o = 0; o < NOB; ++o) w_ += zz[o] * wt_[o]; \
    float sv_ = a_s * s4.COMP; \
    float uu_ = fmaf(LR_IT, g_ - sv_ + w_, sv_); \
    u.COMP = uu_; ssu += uu_ * uu_; su += uu_; }
  #pragma unroll 1
  for (int h0 = 0; h0 < 16; ++h0) {
    float4 s4 = sr4[h0];
    float4 d4 = *(const float4*)&wint[dir * WRS + h0 * 4];
    float4 u;
    STEP_C_ONE(0, x) STEP_C_ONE(1, y) STEP_C_ONE(2, z) STEP_C_ONE(3, w)
    wo4[h0] = u;
  }
  float inv_u = 1.f / (sqrtf(ssu) + EPSV);
  sclW[r] = inv_u;

  float pv_ = a_s * sS - inv_u * su;   // sum(prev_new - s_new) per row
  #pragma unroll
  for (int off = 32; off > 0; off >>= 1) pv_ += __shfl_down(pv_, off);
  if ((t & 63) == 0) red[t >> 6] = pv_;
  __syncthreads();
  if (t == 0) partials[blockIdx.x] = red[0] + red[1] + red[2] + red[3];
}

// ---- final: preds = softmax(s@Wout^T) -> out[:B*32]; normalized s -> out[B*32:] ----
__global__ __launch_bounds__(TPB, 2) void final_kernel(
    const float* __restrict__ buf0, float* __restrict__ out,
    const float* __restrict__ scl0, const float* __restrict__ scl1,
    const float* __restrict__ Wout, const int* __restrict__ actArr)
{
  __shared__ float wot[HH * WOS];
  int t = threadIdx.x;
  stage_wot(Wout, wot, t);
  __syncthreads();

  int n = 0;
  #pragma unroll
  for (int j = 0; j < 10; ++j) n += actArr[j];
  int si = n & 1;
  const float* S   = si ? (out + (size_t)BB * NOB) : buf0;
  const float* scl = si ? scl1 : scl0;

  int r = blockIdx.x * TPB + t;
  float a_s = scl[r];
  const float4* sr4 = (const float4*)(S + (size_t)r * HH);

  float zz[NOB];
  #pragma unroll
  for (int o = 0; o < NOB; ++o) zz[o] = 0.f;
  #pragma unroll 1
  for (int h0 = 0; h0 < 16; ++h0) {
    float4 s4 = sr4[h0];
    const float* t0 = &wot[(h0 * 4 + 0) * WOS];
    const float* t1 = &wot[(h0 * 4 + 1) * WOS];
    const float* t2 = &wot[(h0 * 4 + 2) * WOS];
    const float* t3 = &wot[(h0 * 4 + 3) * WOS];
    #pragma unroll
    for (int o = 0; o < NOB; ++o)
      zz[o] += s4.x * t0[o] + s4.y * t1[o] + s4.z * t2[o] + s4.w * t3[o];
  }
  float m = -1e30f;
  #pragma unroll
  for (int o = 0; o < NOB; ++o) m = fmaxf(m, zz[o]);
  float se = 0.f;
  #pragma unroll
  for (int o = 0; o < NOB; ++o) { zz[o] = __expf(a_s * (zz[o] - m)); se += zz[o]; }
  float rse = 1.f / se;

  float4* po = (float4*)(out + (size_t)r * NOB);
  #pragma unroll
  for (int o4 = 0; o4 < 8; ++o4) {
    float4 f;
    f.x = zz[o4 * 4 + 0] * rse; f.y = zz[o4 * 4 + 1] * rse;
    f.z = zz[o4 * 4 + 2] * rse; f.w = zz[o4 * 4 + 3] * rse;
    po[o4] = f;
  }
  float4* so = (float4*)(out + (size_t)BB * NOB + (size_t)r * HH);
  #pragma unroll 1
  for (int h0 = 0; h0 < 16; ++h0) {
    float4 s4 = sr4[h0];               // read-then-write same addr per thread: safe in-place
    s4.x *= a_s; s4.y *= a_s; s4.z *= a_s; s4.w *= a_s;
    so[h0] = s4;
  }
}

extern "C" void kernel_launch(void* const* d_in, const int* in_sizes, int n_in,
                              void* d_out, int out_size, void* d_ws, size_t ws_size,
                              hipStream_t stream) {
  const int* dirs = (const int*)d_in[0];
  const int* obs = (const int*)d_in[1];
  const float* x = (const float*)d_in[2];
  const float* Wr = (const float*)d_in[3];
  const float* Win = (const float*)d_in[4];
  const float* Wout = (const float*)d_in[5];
  float* out = (float*)d_out;
  float* ws = (float*)d_ws;

  float* buf0 = ws;                              // B*H raw state
  float* sclX = ws + (size_t)BB * HH;            // B (norm scale of x)
  float* scl0 = sclX + BB;                       // B
  float* scl1 = scl0 + BB;                       // B
  float* partials = scl1 + BB;                   // NBLK
  int* actArr = (int*)(partials + NBLK);         // 10 ints
  float* buf1 = out + (size_t)BB * NOB;          // s-slice of d_out doubles as state

  init_kernel<<<NBLK, TPB, 0, stream>>>(x, dirs, Wr, Win, buf0, sclX, scl0, partials);
  for (int k = 0; k < 10; ++k)
    step_kernel<<<NBLK, TPB, 0, stream>>>(x, buf0, buf1, sclX, scl0, scl1,
                                          Wr, Wout, Win, dirs, obs, partials, actArr, k);
  final_kernel<<<NBLK, TPB, 0, stream>>>(buf0, out, scl0, scl1, Wout, actArr);
}

// Round 6
// 190.412 us; speedup vs baseline: 1.2915x; 1.2915x over previous
//
#include <hip/hip_runtime.h>
#include <math.h>

#define BB 131072
#define HH 64
#define NOB 32
#define NDIRS 8
#define LR_IT 1e-3f
#define TOLV 1e-3f
#define EPSV 1e-6f
#define NBLK 512
#define TPB 256
#define WRS 68   // LDS row stride (floats) for Wr / WinT
#define WOS 36   // LDS row stride for WoutT
#define INV_BH (1.0f/8388608.0f)   // 1/(B*H)

// macro params must not be named x/y/z/w (textual expansion vs .x/.y/.z/.w members)
#define D16(pp, Wp, b) ((pp).x*(Wp)[(b)+0] + (pp).y*(Wp)[(b)+1] + (pp).z*(Wp)[(b)+2] + (pp).w*(Wp)[(b)+3])
#define DOT64P(Wp) (D16(p0,Wp,0)+D16(p1,Wp,4)+D16(p2,Wp,8)+D16(p3,Wp,12)+ \
                    D16(p4,Wp,16)+D16(p5,Wp,20)+D16(p6,Wp,24)+D16(p7,Wp,28)+ \
                    D16(p8,Wp,32)+D16(p9,Wp,36)+D16(p10,Wp,40)+D16(p11,Wp,44)+ \
                    D16(p12,Wp,48)+D16(p13,Wp,52)+D16(p14,Wp,56)+D16(p15,Wp,60))
#define LOADP(src) \
  float4 p0=(src)[0], p1=(src)[1], p2=(src)[2], p3=(src)[3], \
         p4=(src)[4], p5=(src)[5], p6=(src)[6], p7=(src)[7], \
         p8=(src)[8], p9=(src)[9], p10=(src)[10], p11=(src)[11], \
         p12=(src)[12], p13=(src)[13], p14=(src)[14], p15=(src)[15];
#define SUMSQ4(pp) ((pp).x*(pp).x + (pp).y*(pp).y + (pp).z*(pp).z + (pp).w*(pp).w)
#define SUM4(pp) ((pp).x + (pp).y + (pp).z + (pp).w)

__device__ __forceinline__ void stage_wr(const float* __restrict__ Wr, float* wrl, int t) {
  const float4* g = (const float4*)Wr;           // Wr row-major [64][64]
  for (int i = t; i < 1024; i += TPB) {
    int h = i >> 4, k4 = i & 15;
    *(float4*)&wrl[h * WRS + k4 * 4] = g[i];
  }
}
__device__ __forceinline__ void stage_wot(const float* __restrict__ Wout, float* wot, int t) {
  for (int i = t; i < NOB * HH; i += TPB) {      // Wout [32][64] -> wot[h][o]
    int o = i >> 6, h = i & 63;
    wot[h * WOS + o] = Wout[i];
  }
}
__device__ __forceinline__ void stage_wint(const float* __restrict__ Win, float* wint, int t) {
  for (int i = t; i < HH * NDIRS; i += TPB) {    // Win [64][8] -> wint[d][h]
    int h = i >> 3, d = i & 7;
    wint[d * WRS + h] = Win[i];
  }
}

// wave-shuffle + LDS block reduction; returns block total to ALL threads.
__device__ __forceinline__ float block_reduce_all(float v, float* red, int t) {
  #pragma unroll
  for (int off = 32; off > 0; off >>= 1) v += __shfl_down(v, off);
  __syncthreads();                   // guard red[] from any previous use
  if ((t & 63) == 0) red[t >> 6] = v;
  __syncthreads();
  return red[0] + red[1] + red[2] + red[3];
}

// preds = softmax(a_s * S_raw @ wot) -> out[:B*32]; a_s*S_raw -> out[B*32:]
__device__ __forceinline__ void final_write(
    int r, float a_s, const float* __restrict__ S, float* __restrict__ out,
    const float* wot) {
  const float4* __restrict__ sr4 = (const float4*)(S + (size_t)r * HH);
  float zz[NOB];
  #pragma unroll
  for (int o = 0; o < NOB; ++o) zz[o] = 0.f;
  #pragma unroll 1
  for (int h0 = 0; h0 < 16; ++h0) {
    float4 s4 = sr4[h0];
    const float* t0 = &wot[(h0 * 4 + 0) * WOS];
    const float* t1 = &wot[(h0 * 4 + 1) * WOS];
    const float* t2 = &wot[(h0 * 4 + 2) * WOS];
    const float* t3 = &wot[(h0 * 4 + 3) * WOS];
    #pragma unroll
    for (int o = 0; o < NOB; ++o)
      zz[o] += s4.x * t0[o] + s4.y * t1[o] + s4.z * t2[o] + s4.w * t3[o];
  }
  float m = -1e30f;
  #pragma unroll
  for (int o = 0; o < NOB; ++o) m = fmaxf(m, zz[o]);
  float se = 0.f;
  #pragma unroll
  for (int o = 0; o < NOB; ++o) { zz[o] = __expf(a_s * (zz[o] - m)); se += zz[o]; }
  float rse = 1.f / se;

  float4* po = (float4*)(out + (size_t)r * NOB);
  #pragma unroll
  for (int o4 = 0; o4 < 8; ++o4) {
    float4 f;
    f.x = zz[o4 * 4 + 0] * rse; f.y = zz[o4 * 4 + 1] * rse;
    f.z = zz[o4 * 4 + 2] * rse; f.w = zz[o4 * 4 + 3] * rse;
    po[o4] = f;
  }
  float4* so = (float4*)(out + (size_t)BB * NOB + (size_t)r * HH);
  #pragma unroll 1
  for (int h0 = 0; h0 < 16; ++h0) {
    float4 s4 = sr4[h0];    // in-place safe: same thread reads then writes same addr
    s4.x *= a_s; s4.y *= a_s; s4.z *= a_s; s4.w *= a_s;
    so[h0] = s4;
  }
}

// ---- init: prev=norm(x) implicit (x + sclX); s0 raw -> buf0, scale -> scl0 ----
__global__ __launch_bounds__(TPB, 2) void init_kernel(
    const float* __restrict__ x, const int* __restrict__ dirs,
    const float* __restrict__ Wr, const float* __restrict__ Win,
    float* __restrict__ buf0, float* __restrict__ sclX, float* __restrict__ scl0,
    float* __restrict__ partials)
{
  __shared__ float wrl[HH * WRS];
  __shared__ float wint[NDIRS * WRS];
  __shared__ float red[4];
  int t = threadIdx.x;
  stage_wr(Wr, wrl, t);
  stage_wint(Win, wint, t);
  __syncthreads();

  int r = blockIdx.x * TPB + t;
  const float4* __restrict__ xr = (const float4*)(x + (size_t)r * HH);
  LOADP(xr);

  float ssx = SUMSQ4(p0)+SUMSQ4(p1)+SUMSQ4(p2)+SUMSQ4(p3)+SUMSQ4(p4)+SUMSQ4(p5)+
              SUMSQ4(p6)+SUMSQ4(p7)+SUMSQ4(p8)+SUMSQ4(p9)+SUMSQ4(p10)+SUMSQ4(p11)+
              SUMSQ4(p12)+SUMSQ4(p13)+SUMSQ4(p14)+SUMSQ4(p15);
  float sx  = SUM4(p0)+SUM4(p1)+SUM4(p2)+SUM4(p3)+SUM4(p4)+SUM4(p5)+SUM4(p6)+SUM4(p7)+
              SUM4(p8)+SUM4(p9)+SUM4(p10)+SUM4(p11)+SUM4(p12)+SUM4(p13)+SUM4(p14)+SUM4(p15);
  float inv_x = 1.f / (sqrtf(ssx) + EPSV);
  int dir = dirs[r];

  float4* bo = (float4*)(buf0 + (size_t)r * HH);
  float ssg = 0.f, sg = 0.f;
#define INIT_ONE(JJ, COMP) { \
    const float* wr_ = &wrl[(h0 * 4 + JJ) * WRS]; \
    u.COMP = fmaxf(fmaf(inv_x, DOT64P(wr_), d4.COMP), 0.f); }
  #pragma unroll 1
  for (int h0 = 0; h0 < 16; ++h0) {
    float4 d4 = *(const float4*)&wint[dir * WRS + h0 * 4];
    float4 u;
    INIT_ONE(0, x) INIT_ONE(1, y) INIT_ONE(2, z) INIT_ONE(3, w)
    bo[h0] = u;
    ssg += SUMSQ4(u); sg += SUM4(u);
  }
  float inv_g = 1.f / (sqrtf(ssg) + EPSV);
  sclX[r] = inv_x;
  scl0[r] = inv_g;

  float tot = block_reduce_all(inv_x * sx - inv_g * sg, red, t);
  if (t == 0) partials[blockIdx.x] = tot;
}

// ---- launch k: gate + (active step | first-inactive final-write | no-op) ----
// Sticky gate => at any launch that is active or first-inactive, #prior-active == k.
__global__ __launch_bounds__(TPB, 2) void step_kernel(
    const float* __restrict__ x,
    float* __restrict__ buf0, float* __restrict__ buf1,
    const float* __restrict__ sclX, float* __restrict__ scl0, float* __restrict__ scl1,
    const float* __restrict__ Wr, const float* __restrict__ Wout, const float* __restrict__ Win,
    const int* __restrict__ dirs, const int* __restrict__ obs,
    float* __restrict__ partials, int* __restrict__ actArr,
    float* __restrict__ out, int k)
{
  __shared__ float red[4];
  __shared__ float wrl[HH * WRS];
  __shared__ float wot[HH * WOS];
  __shared__ float wint[NDIRS * WRS];
  int t = threadIdx.x;

  // gate: every block reduces the identical 512 partials -> uniform decision
  float tot = block_reduce_all(partials[t] + partials[t + TPB], red, t);
  int active = (fabsf(tot * INV_BH) > TOLV) ? 1 : 0;
  if (blockIdx.x == 0 && t == 0) actArr[k] = active;

  int si = k & 1;
  int r = blockIdx.x * TPB + t;

  if (!active) {
    int first_inactive = (k == 0) ? 1 : actArr[k - 1];   // written by previous launch
    if (!first_inactive) return;                          // uniform: no barrier skipped
    stage_wot(Wout, wot, t);
    __syncthreads();
    const float* S   = si ? buf1 : buf0;
    const float* scl = si ? scl1 : scl0;
    final_write(r, scl[r], S, out, wot);
    return;
  }

  const float* S    = si ? buf1 : buf0;
  const float* sclS = si ? scl1 : scl0;
  float* W          = si ? buf0 : buf1;          // prev slot, overwritten with new s
  float* sclW       = si ? scl0 : scl1;
  const float* P    = (k == 0) ? x    : W;       // prev state rows (this thread's own)
  const float* sclP = (k == 0) ? sclX : sclW;

  stage_wr(Wr, wrl, t);
  stage_wot(Wout, wot, t);
  stage_wint(Win, wint, t);
  __syncthreads();

  float a_s = sclS[r];
  float a_p = sclP[r];
  int ob = obs[r];
  int dir = dirs[r];
  const float4* __restrict__ sr4 = (const float4*)(S + (size_t)r * HH);

  // ---- phase A: logits (raw scale) — small live set (zz only) ----
  float zz[NOB];
  #pragma unroll
  for (int o = 0; o < NOB; ++o) zz[o] = 0.f;
  float sS = 0.f;
  #pragma unroll 1
  for (int h0 = 0; h0 < 16; ++h0) {
    float4 s4 = sr4[h0];
    sS += SUM4(s4);
    const float* t0 = &wot[(h0 * 4 + 0) * WOS];
    const float* t1 = &wot[(h0 * 4 + 1) * WOS];
    const float* t2 = &wot[(h0 * 4 + 2) * WOS];
    const float* t3 = &wot[(h0 * 4 + 3) * WOS];
    #pragma unroll
    for (int o = 0; o < NOB; ++o)
      zz[o] += s4.x * t0[o] + s4.y * t1[o] + s4.z * t2[o] + s4.w * t3[o];
  }

  // softmax (max commutes with positive scale a_s), then zz -> jp in place
  float m = -1e30f;
  #pragma unroll
  for (int o = 0; o < NOB; ++o) m = fmaxf(m, zz[o]);
  float se = 0.f;
  #pragma unroll
  for (int o = 0; o < NOB; ++o) { zz[o] = __expf(a_s * (zz[o] - m)); se += zz[o]; }
  float rse = 1.f / se;
  float fob = 0.f, sf2 = 0.f;
  #pragma unroll
  for (int o = 0; o < NOB; ++o) {
    float f = zz[o] * rse;
    zz[o] = f;
    sf2 += f * f;
    fob += (o == ob) ? f : 0.f;
  }
  float fe = fob - sf2;
  #pragma unroll
  for (int o = 0; o < NOB; ++o) {
    float ep = ((o == ob) ? 1.f : 0.f) - zz[o];
    zz[o] = zz[o] * (ep - fe);   // jp
  }

  __syncthreads();   // live-range firewall: P row enters registers only after phase A

  // ---- phase B+C fused: u = s + LR*(relu(a_p*dot64(P,Wr_h)+drive_h) - s + dot32(jp,wot_h)) ----
  const float4* __restrict__ pr4 = (const float4*)(P + (size_t)r * HH);
  LOADP(pr4);
  float4* wo4 = (float4*)(W + (size_t)r * HH);
  float ssu = 0.f, su = 0.f;
#define STEP_C_ONE(JJ, COMP) { \
    const float* wr_ = &wrl[(h0 * 4 + JJ) * WRS]; \
    float g_ = fmaxf(fmaf(a_p, DOT64P(wr_), d4.COMP), 0.f); \
    const float* wt_ = &wot[(h0 * 4 + JJ) * WOS]; \
    float w_ = 0.f; \
    _Pragma("unroll") \
    for (int o = 0; o < NOB; ++o) w_ += zz[o] * wt_[o]; \
    float sv_ = a_s * s4.COMP; \
    float uu_ = fmaf(LR_IT, g_ - sv_ + w_, sv_); \
    u.COMP = uu_; ssu += uu_ * uu_; su += uu_; }
  #pragma unroll 1
  for (int h0 = 0; h0 < 16; ++h0) {
    float4 s4 = sr4[h0];
    float4 d4 = *(const float4*)&wint[dir * WRS + h0 * 4];
    float4 u;
    STEP_C_ONE(0, x) STEP_C_ONE(1, y) STEP_C_ONE(2, z) STEP_C_ONE(3, w)
    wo4[h0] = u;
  }
  float inv_u = 1.f / (sqrtf(ssu) + EPSV);
  sclW[r] = inv_u;

  float tot2 = block_reduce_all(a_s * sS - inv_u * su, red, t);
  if (t == 0) partials[blockIdx.x] = tot2;
}

// ---- tail: only fires when all 10 steps were active ----
__global__ __launch_bounds__(TPB, 2) void final_kernel(
    const float* __restrict__ buf0, float* __restrict__ out,
    const float* __restrict__ scl0,
    const float* __restrict__ Wout, const int* __restrict__ actArr)
{
  if (actArr[9] == 0) return;          // uniform: final already written by first-inactive step
  __shared__ float wot[HH * WOS];
  int t = threadIdx.x;
  stage_wot(Wout, wot, t);
  __syncthreads();
  // 10 active steps: s10 lives in buf0/scl0 (parity 10&1==0)
  int r = blockIdx.x * TPB + t;
  final_write(r, scl0[r], buf0, out, wot);
}

extern "C" void kernel_launch(void* const* d_in, const int* in_sizes, int n_in,
                              void* d_out, int out_size, void* d_ws, size_t ws_size,
                              hipStream_t stream) {
  const int* dirs = (const int*)d_in[0];
  const int* obs = (const int*)d_in[1];
  const float* x = (const float*)d_in[2];
  const float* Wr = (const float*)d_in[3];
  const float* Win = (const float*)d_in[4];
  const float* Wout = (const float*)d_in[5];
  float* out = (float*)d_out;
  float* ws = (float*)d_ws;

  float* buf0 = ws;                              // B*H raw state
  float* sclX = ws + (size_t)BB * HH;            // B
  float* scl0 = sclX + BB;                       // B
  float* scl1 = scl0 + BB;                       // B
  float* partials = scl1 + BB;                   // NBLK
  int* actArr = (int*)(partials + NBLK);         // 10 ints
  float* buf1 = out + (size_t)BB * NOB;          // s-slice of d_out doubles as state

  init_kernel<<<NBLK, TPB, 0, stream>>>(x, dirs, Wr, Win, buf0, sclX, scl0, partials);
  for (int k = 0; k < 10; ++k)
    step_kernel<<<NBLK, TPB, 0, stream>>>(x, buf0, buf1, sclX, scl0, scl1,
                                          Wr, Wout, Win, dirs, obs, partials, actArr, out, k);
  final_kernel<<<NBLK, TPB, 0, stream>>>(buf0, out, scl0, Wout, actArr);
}